// Round 3
// baseline (2551.776 us; speedup 1.0000x reference)
//
#include <hip/hip_runtime.h>
#include <cstddef>
#include <cstdint>

// Problem constants
#define B_ 64
#define T_ 128
#define N_ 64
#define D_ 64
#define Q_ 5
#define E_ 8
#define P_ 768
#define H_ 128

typedef _Float16 f16;
typedef _Float16 f16x2 __attribute__((ext_vector_type(2)));
typedef _Float16 f16x4 __attribute__((ext_vector_type(4)));
typedef _Float16 f16x8 __attribute__((ext_vector_type(8)));
typedef float f32x4 __attribute__((ext_vector_type(4)));

__device__ __forceinline__ float fast_sig(float x) {
  return 1.f / (1.f + __expf(-x));
}
__device__ __forceinline__ float fast_tanh(float x) {
  // NaN-free for large |x|
  return 1.f - 2.f / (1.f + __expf(2.f * x));
}

// ---------------------------------------------------------------------------
// K1: per-node MLPs -> qv (N,Q) and row-normalized ne (N,E). One block per n.
// f-hidden and g-hidden computed concurrently by thread halves.
// ---------------------------------------------------------------------------
__global__ void k_mlps(const float* __restrict__ vpr,
                       const float* __restrict__ Wf1, const float* __restrict__ bf1,
                       const float* __restrict__ Wf2, const float* __restrict__ bf2,
                       const float* __restrict__ Wg1, const float* __restrict__ bg1,
                       const float* __restrict__ Wg2, const float* __restrict__ bg2,
                       float* __restrict__ qv, float* __restrict__ neb) {
  int n = blockIdx.x;
  int tid = threadIdx.x;  // 256
  __shared__ float v[P_];
  __shared__ float hf[H_];
  __shared__ float hg[H_];
  __shared__ float tmp[E_];

  for (int i = tid; i < P_; i += 256) v[i] = vpr[n * P_ + i];
  __syncthreads();

  if (tid < H_) {
    int j = tid;
    float a = bf1[j];
#pragma unroll 8
    for (int i = 0; i < P_; ++i) a += v[i] * Wf1[i * H_ + j];
    hf[j] = fmaxf(a, 0.f);
  } else {
    int j = tid - H_;
    float a = bg1[j];
#pragma unroll 8
    for (int i = 0; i < P_; ++i) a += v[i] * Wg1[i * H_ + j];
    hg[j] = fmaxf(a, 0.f);
  }
  __syncthreads();
  if (tid < Q_) {
    float a = bf2[tid];
    for (int j = 0; j < H_; ++j) a += hf[j] * Wf2[j * Q_ + tid];
    qv[n * Q_ + tid] = a;
  } else if (tid >= 8 && tid < 8 + E_) {
    int e = tid - 8;
    float a = bg2[e];
    for (int j = 0; j < H_; ++j) a += hg[j] * Wg2[j * E_ + e];
    tmp[e] = a;
  }
  __syncthreads();
  if (tid == 0) {
    float s = 0.f;
    for (int e = 0; e < E_; ++e) s += tmp[e] * tmp[e];
    float r = 1.f / sqrtf(s);
    for (int e = 0; e < E_; ++e) neb[n * E_ + e] = tmp[e] * r;
  }
}

// ---------------------------------------------------------------------------
// K2: adj row softmax -> adjP = f16x2{adj, adj*rarw}; per-node gate biases and
// rs-column weights (rank-1 fold of feature f=64). One block (64 thr) per n.
// ---------------------------------------------------------------------------
__global__ void k_meta(const float* __restrict__ neb, const float* __restrict__ qv,
                       const float* __restrict__ br, const float* __restrict__ bu,
                       const float* __restrict__ bc,
                       const float* __restrict__ Wr, const float* __restrict__ Wu,
                       const float* __restrict__ Wc, const float* __restrict__ rarw,
                       f16x2* __restrict__ adjP, float* __restrict__ brn,
                       float* __restrict__ bun, float* __restrict__ bcn,
                       float* __restrict__ WrsR, float* __restrict__ WrsU,
                       float* __restrict__ WrsC) {
  int n = blockIdx.x;
  int j = threadIdx.x;  // 64 = one wave
  float s = 0.f;
#pragma unroll
  for (int e = 0; e < E_; ++e) s += neb[n * E_ + e] * neb[j * E_ + e];
  float m = s;
  for (int off = 32; off; off >>= 1) m = fmaxf(m, __shfl_xor(m, off));
  float ex = __expf(s - m);
  float sum = ex;
  for (int off = 32; off; off >>= 1) sum += __shfl_xor(sum, off);
  float av = ex / sum;
  adjP[n * N_ + j] = f16x2{(f16)av, (f16)(av * rarw[n * N_ + j])};

  float pr = 0.f, pu = 0.f, pc = 0.f;
  float wr = 0.f, wu = 0.f, wc = 0.f;
#pragma unroll
  for (int q = 0; q < Q_; ++q) {
    float qq = qv[n * Q_ + q];
    pr += qq * br[q * D_ + j];
    pu += qq * bu[q * D_ + j];
    pc += qq * bc[q * D_ + j];
    wr += qq * Wr[((size_t)q * 129 + 64) * D_ + j];
    wu += qq * Wu[((size_t)q * 129 + 64) * D_ + j];
    wc += qq * Wc[((size_t)q * 129 + 64) * D_ + j];
  }
  brn[n * D_ + j] = pr;
  bun[n * D_ + j] = pu;
  bcn[n * D_ + j] = pc;
  WrsR[n * D_ + j] = wr;
  WrsU[n * D_ + j] = wu;
  WrsC[n * D_ + j] = wc;
}

// ---------------------------------------------------------------------------
// K3: pack shared gate weights into MFMA B-fragment order, fp16 (HW-verified
// in round 2 — do not change).
// frag id = ((g*5+q)*4+kt)*4+nt ; within frag lane l holds 8 f16:
//   B[k = 32*kt + 8*(l>>4) + e][col = 16*nt + (l&15)],  f = k + (k>=64)
// ---------------------------------------------------------------------------
__global__ void k_pack(const float* __restrict__ Wr, const float* __restrict__ Wu,
                       const float* __restrict__ Wc, f16* __restrict__ Wpk) {
  int bid = blockIdx.x;           // 240 = 3*5*4*4
  int nt = bid & 3;
  int kt = (bid >> 2) & 3;
  int q = (bid >> 4) % 5;
  int g = bid / 80;
  const float* W = (g == 0) ? Wr : ((g == 1) ? Wu : Wc);
  int l = threadIdx.x;            // 64
  int co = 16 * nt + (l & 15);
  f16* dst = Wpk + (size_t)bid * 512 + l * 8;
#pragma unroll
  for (int e = 0; e < 8; ++e) {
    int k = 32 * kt + 8 * (l >> 4) + e;
    int f = k + (k >= 64);
    dst[e] = (f16)W[((size_t)q * 129 + f) * D_ + co];
  }
}

// ---------------------------------------------------------------------------
// K4: var_total[b][n]
// ---------------------------------------------------------------------------
__global__ void k_vt(const float* __restrict__ mask, float* __restrict__ vt) {
  int b = blockIdx.x;
  int n = threadIdx.x;  // 64
  float s = 0.f;
  for (int t = 0; t < T_; ++t) s += mask[(b * T_ + t) * N_ + n];
  vt[b * N_ + n] = s;
}

// ---------------------------------------------------------------------------
// SEQ: one 512-thread block (8 waves) per batch, 2 waves/SIMD, 256 VGPR/wave.
// All gate-weight fragments live in registers for the whole T-loop.
// Waves 0-3 ("U"): u-gate + c-x-half for out-col tile nt=wv; hold h, u in
//   MFMA C-layout registers and do all GRU elementwise math.
// Waves 4-7 ("R"): r-gate + c-h-half for nt=wv-4.
// LDS 64.8 KB static.
// ---------------------------------------------------------------------------
__launch_bounds__(512, 1)
__global__ void k_seq(const float* __restrict__ obs, const float* __restrict__ mask,
                      const int* __restrict__ lengths, const float* __restrict__ ai,
                      const f16x2* __restrict__ adjP,
                      const float* __restrict__ brn, const float* __restrict__ bun,
                      const float* __restrict__ bcn, const float* __restrict__ WrsR,
                      const float* __restrict__ WrsU, const float* __restrict__ WrsC,
                      const float* __restrict__ qv, const float* __restrict__ vt,
                      const f16* __restrict__ Wpk, float* __restrict__ out) {
  // combT: [k 0..127][node j], stride 72. rows 0..63 = x(d), 64..127 = h(d)
  __shared__ __align__(16) f16 combT[128 * 72];   // 18432
  // actA: [n][k] stride 136. P2 writes msg; P4 overwrites cols 64..127 = h_r
  __shared__ __align__(16) f16 actA[64 * 136];    // 17408
  __shared__ __align__(16) f16 xA[64 * 72];       //  9216  x row-major [n][d]
  // AP: A-matrix [i][j] stride 72 (P1b..P2); then r~ preR [n][o] stride 68 (P3..P4)
  __shared__ __align__(16) f16 AP[64 * 72];       //  9216
  __shared__ __align__(16) f16 pCH[64 * 68];      //  8704  c h-half partial (+bC+rs*wC)
  __shared__ __align__(16) f16 qvS[64 * 8];       //  1024
  __shared__ float rsS[N_];
  __shared__ float mS[N_];
  __shared__ float mrS[N_];

  const int tid = threadIdx.x;
  const int b = blockIdx.x;
  const int lane = tid & 63;
  const int wv = tid >> 6;       // 8 waves
  const int lm = lane & 15;
  const int lq = lane >> 4;
  const bool isU = (wv < 4);
  const int nt = wv & 3;
  const int oc = 16 * nt + lm;   // this wave's output column

  // ---- persistent weight fragments (roles: U: u + c-x | R: r + c-h) ----
  f16x8 wA[4][5];  // U: u-gate kt 0..3 | R: r-gate kt 0..3
  f16x8 wB[2][5];  // U: c-gate kt 0..1 (x-half) | R: c-gate kt 2..3 (h-half)
  {
    const int gA = isU ? 1 : 0;
    const int ktB0 = isU ? 0 : 2;
#pragma unroll
    for (int kt = 0; kt < 4; ++kt)
#pragma unroll
      for (int q = 0; q < 5; ++q)
        wA[kt][q] = *(const f16x8*)(Wpk +
            ((size_t)(((gA * 5 + q) * 4 + kt) * 4 + nt) * 64 + lane) * 8);
#pragma unroll
    for (int kk = 0; kk < 2; ++kk)
#pragma unroll
      for (int q = 0; q < 5; ++q)
        wB[kk][q] = *(const f16x8*)(Wpk +
            ((size_t)(((2 * 5 + q) * 4 + (ktB0 + kk)) * 4 + nt) * 64 + lane) * 8);
  }

  // ---- persistent bias packs (per-lane 16 (n,o) cells in C-layout) ----
  // b1/b2: U: bU,wU | R: bR,wR.  b3/b4: R only: bC,wC.
  f16x2 b1[8], b2[8], b3[8], b4[8];
  {
    const float* p1 = isU ? bun : brn;
    const float* p2 = isU ? WrsU : WrsR;
#pragma unroll
    for (int mt = 0; mt < 4; ++mt)
#pragma unroll
      for (int ii = 0; ii < 2; ++ii) {
        int n0 = 16 * mt + 4 * lq + 2 * ii;
        b1[mt * 2 + ii] = f16x2{(f16)p1[n0 * D_ + oc], (f16)p1[(n0 + 1) * D_ + oc]};
        b2[mt * 2 + ii] = f16x2{(f16)p2[n0 * D_ + oc], (f16)p2[(n0 + 1) * D_ + oc]};
        if (!isU) {
          b3[mt * 2 + ii] = f16x2{(f16)bcn[n0 * D_ + oc], (f16)bcn[(n0 + 1) * D_ + oc]};
          b4[mt * 2 + ii] = f16x2{(f16)WrsC[n0 * D_ + oc], (f16)WrsC[(n0 + 1) * D_ + oc]};
        } else {
          b3[mt * 2 + ii] = f16x2{(f16)0.f, (f16)0.f};
          b4[mt * 2 + ii] = f16x2{(f16)0.f, (f16)0.f};
        }
      }
  }

  // adjacency rows for this thread's 8 A-entries (i = tid>>3, j = 8*(tid&7)+k)
  f16x2 adjR[8];
  {
    const f16x2* arow = adjP + (tid >> 3) * N_ + 8 * (tid & 7);
#pragma unroll
    for (int k = 0; k < 8; ++k) adjR[k] = arow[k];
  }

  // qvS (f-padded to 8)
  qvS[tid] = ((tid & 7) < Q_) ? (f16)qv[(tid >> 3) * Q_ + (tid & 7)] : (f16)0.f;
  // zero combT h-rows (h(0) = 0)
  for (int i = tid; i < 64 * 72; i += 512) combT[64 * 72 + i] = (f16)0.f;

  // persistent fp32 hidden state (U waves, C-layout)
  f32x4 h[4];
#pragma unroll
  for (int mt = 0; mt < 4; ++mt) h[mt] = f32x4{0.f, 0.f, 0.f, 0.f};

  // prefetch t=0 inputs
  const float* xbase = obs + (size_t)b * T_ * (N_ * D_);
  float4 xc0 = *(const float4*)(xbase + tid * 8);
  float4 xc1 = *(const float4*)(xbase + tid * 8 + 4);
  float mCur = 0.f, aCur = 0.f, vtR = 0.f;
  if (tid < N_) {
    vtR = vt[b * N_ + tid];
    mCur = mask[(b * T_) * N_ + tid];
    aCur = ai[(b * T_) * N_ + tid];
  }
  const int lenm1 = lengths[b] - 1;
  __syncthreads();

  for (int t = 0; t < T_; ++t) {
    // ---- P0: rs/mask + x staging (row-major); prefetch t+1 ----
    if (tid < N_) {
      mS[tid] = mCur;
      rsS[tid] = 0.5f * fast_tanh(aCur / (vtR + 1.f));
    }
    {
      int n = tid >> 3, d0 = 8 * (tid & 7);
      f16x8 xh = {(f16)xc0.x, (f16)xc0.y, (f16)xc0.z, (f16)xc0.w,
                  (f16)xc1.x, (f16)xc1.y, (f16)xc1.z, (f16)xc1.w};
      *(f16x8*)(xA + n * 72 + d0) = xh;
    }
    if (t + 1 < T_) {
      const float* xn = xbase + (size_t)(t + 1) * (N_ * D_) + tid * 8;
      xc0 = *(const float4*)xn;
      xc1 = *(const float4*)(xn + 4);
      if (tid < N_) {
        mCur = mask[(b * T_ + t + 1) * N_ + tid];
        aCur = ai[(b * T_ + t + 1) * N_ + tid];
      }
    }
    __syncthreads();

    // ---- P1b: build A (f16) + x-transpose into combT ----
    {
      int i = tid >> 3, j0 = 8 * (tid & 7);
      float ri = rsS[i], mi = mS[i];
      float4 rj0 = *(const float4*)&rsS[j0];
      float4 rj1 = *(const float4*)&rsS[j0 + 4];
      float4 mj0 = *(const float4*)&mS[j0];
      float4 mj1 = *(const float4*)&mS[j0 + 4];
      float rj[8] = {rj0.x, rj0.y, rj0.z, rj0.w, rj1.x, rj1.y, rj1.z, rj1.w};
      float mj[8] = {mj0.x, mj0.y, mj0.z, mj0.w, mj1.x, mj1.y, mj1.z, mj1.w};
      f16x8 av;
#pragma unroll
      for (int k = 0; k < 8; ++k) {
        float a = ((float)adjR[k][0] - (float)adjR[k][1] * fabsf(ri - rj[k])) * mi * mj[k];
        if (i == j0 + k) a = 1.f;
        av[k] = (f16)a;
      }
      *(f16x8*)(AP + i * 72 + j0) = av;

      // transpose x: this thread handles feature d = tid>>3, nodes n0..n0+7
      int d = tid >> 3, n0 = 8 * (tid & 7);
      f16x8 tx;
#pragma unroll
      for (int k = 0; k < 8; ++k) tx[k] = xA[(n0 + k) * 72 + d];
      *(f16x8*)(combT + d * 72 + n0) = tx;
    }
    __syncthreads();

    // ---- P2: msg = A @ comb (MFMA, 32 tiles / 8 waves) + mr GEMV ----
    {
#pragma unroll
      for (int s = 0; s < 4; ++s) {
        int tt = wv * 4 + s;
        int mt = tt >> 3, ft = tt & 7;
        f32x4 acc = {0.f, 0.f, 0.f, 0.f};
#pragma unroll
        for (int kt = 0; kt < 2; ++kt) {
          f16x8 aF = *(const f16x8*)(AP + (lm + 16 * mt) * 72 + 8 * lq + 32 * kt);
          f16x8 bF = *(const f16x8*)(combT + (lm + 16 * ft) * 72 + 8 * lq + 32 * kt);
          acc = __builtin_amdgcn_mfma_f32_16x16x32_f16(aF, bF, acc, 0, 0, 0);
        }
        int row = 16 * mt + 4 * lq;
        int col = 16 * ft + lm;
        actA[(row + 0) * 136 + col] = (f16)acc[0];
        actA[(row + 1) * 136 + col] = (f16)acc[1];
        actA[(row + 2) * 136 + col] = (f16)acc[2];
        actA[(row + 3) * 136 + col] = (f16)acc[3];
      }
      // mr[n] = sum_j A[n,j]*rs[j]
      int n = tid >> 3, j0 = 8 * (tid & 7);
      f16x8 a8 = *(const f16x8*)(AP + n * 72 + j0);
      float4 r0 = *(const float4*)&rsS[j0];
      float4 r1 = *(const float4*)&rsS[j0 + 4];
      float s = (float)a8[0] * r0.x + (float)a8[1] * r0.y + (float)a8[2] * r0.z +
                (float)a8[3] * r0.w + (float)a8[4] * r1.x + (float)a8[5] * r1.y +
                (float)a8[6] * r1.z + (float)a8[7] * r1.w;
      s += __shfl_xor(s, 1);
      s += __shfl_xor(s, 2);
      s += __shfl_xor(s, 4);
      if ((lane & 7) == 0) mrS[n] = s;
    }
    __syncthreads();

    // ---- P3: main gate GEMM (U: u | R: r) over msg, K=128 ----
    f32x4 gacc[4];
#pragma unroll
    for (int mt = 0; mt < 4; ++mt) gacc[mt] = f32x4{0.f, 0.f, 0.f, 0.f};
    {
      f16x8 qh[4];
#pragma unroll
      for (int mt = 0; mt < 4; ++mt)
        qh[mt] = *(const f16x8*)(qvS + (lm + 16 * mt) * 8);
#pragma unroll
      for (int kt = 0; kt < 4; ++kt) {
        f16x8 aF[4];
#pragma unroll
        for (int mt = 0; mt < 4; ++mt)
          aF[mt] = *(const f16x8*)(actA + (lm + 16 * mt) * 136 + 8 * lq + 32 * kt);
#pragma unroll
        for (int q = 0; q < 5; ++q) {
          f16x8 wF = wA[kt][q];
#pragma unroll
          for (int mt = 0; mt < 4; ++mt) {
            f16x8 as = aF[mt] * qh[mt][q];
            gacc[mt] = __builtin_amdgcn_mfma_f32_16x16x32_f16(as, wF, gacc[mt], 0, 0, 0);
          }
        }
      }
    }
    if (!isU) {
      // r~ = sigmoid(racc + bR + mr*wR) -> preR (AP region, stride 68)
#pragma unroll
      for (int mt = 0; mt < 4; ++mt) {
        float4 mr4 = *(const float4*)&mrS[16 * mt + 4 * lq];
#pragma unroll
        for (int i = 0; i < 4; ++i) {
          float bb = (float)b1[mt * 2 + (i >> 1)][i & 1];
          float ww = (float)b2[mt * 2 + (i >> 1)][i & 1];
          float v = gacc[mt][i] + bb + mr4[i] * ww;
          AP[(16 * mt + 4 * lq + i) * 68 + oc] = (f16)fast_sig(v);
        }
      }
    }
    __syncthreads();

    // ---- P4: U waves: u gate, h_r; write actA h_r cols ----
    f16x2 upk[8];
    if (isU) {
#pragma unroll
      for (int mt = 0; mt < 4; ++mt) {
        float4 mr4 = *(const float4*)&mrS[16 * mt + 4 * lq];
        float4 m4 = *(const float4*)&mS[16 * mt + 4 * lq];
#pragma unroll
        for (int i = 0; i < 4; ++i) {
          int row = 16 * mt + 4 * lq + i;
          float bb = (float)b1[mt * 2 + (i >> 1)][i & 1];
          float ww = (float)b2[mt * 2 + (i >> 1)][i & 1];
          float u = fast_sig(gacc[mt][i] + bb + mr4[i] * ww);
          float rt = (float)AP[row * 68 + oc];
          float hr = (m4[i] > 0.f) ? rt * h[mt][i] : h[mt][i];
          upk[mt * 2 + (i >> 1)][i & 1] = (f16)u;
          actA[row * 136 + 64 + oc] = (f16)hr;
        }
      }
    }
    __syncthreads();

    // ---- P5: c-gate halves (U: x-half -> regs | R: h-half -> pCH) ----
    f32x4 cacc[4];
#pragma unroll
    for (int mt = 0; mt < 4; ++mt) cacc[mt] = f32x4{0.f, 0.f, 0.f, 0.f};
    {
      f16x8 qh[4];
#pragma unroll
      for (int mt = 0; mt < 4; ++mt)
        qh[mt] = *(const f16x8*)(qvS + (lm + 16 * mt) * 8);
      if (isU) {
#pragma unroll
        for (int kk = 0; kk < 2; ++kk) {
          f16x8 aF[4];
#pragma unroll
          for (int mt = 0; mt < 4; ++mt)
            aF[mt] = *(const f16x8*)(xA + (lm + 16 * mt) * 72 + 8 * lq + 32 * kk);
#pragma unroll
          for (int q = 0; q < 5; ++q) {
            f16x8 wF = wB[kk][q];
#pragma unroll
            for (int mt = 0; mt < 4; ++mt) {
              f16x8 as = aF[mt] * qh[mt][q];
              cacc[mt] = __builtin_amdgcn_mfma_f32_16x16x32_f16(as, wF, cacc[mt], 0, 0, 0);
            }
          }
        }
      } else {
#pragma unroll
        for (int kk = 0; kk < 2; ++kk) {
          int kt = 2 + kk;
          f16x8 aF[4];
#pragma unroll
          for (int mt = 0; mt < 4; ++mt)
            aF[mt] = *(const f16x8*)(actA + (lm + 16 * mt) * 136 + 8 * lq + 32 * kt);
#pragma unroll
          for (int q = 0; q < 5; ++q) {
            f16x8 wF = wB[kk][q];
#pragma unroll
            for (int mt = 0; mt < 4; ++mt) {
              f16x8 as = aF[mt] * qh[mt][q];
              cacc[mt] = __builtin_amdgcn_mfma_f32_16x16x32_f16(as, wF, cacc[mt], 0, 0, 0);
            }
          }
        }
        // fold bC + rs*wC into h-half partial, write pCH
#pragma unroll
        for (int mt = 0; mt < 4; ++mt) {
          float4 rs4 = *(const float4*)&rsS[16 * mt + 4 * lq];
#pragma unroll
          for (int i = 0; i < 4; ++i) {
            float bb = (float)b3[mt * 2 + (i >> 1)][i & 1];
            float ww = (float)b4[mt * 2 + (i >> 1)][i & 1];
            float v = cacc[mt][i] + bb + rs4[i] * ww;
            pCH[(16 * mt + 4 * lq + i) * 68 + oc] = (f16)v;
          }
        }
      }
    }
    __syncthreads();

    // ---- P6: U waves: cand, h update, combT h-rows, output ----
    if (isU) {
#pragma unroll
      for (int mt = 0; mt < 4; ++mt) {
        float4 m4 = *(const float4*)&mS[16 * mt + 4 * lq];
        f16x4 hquad;
#pragma unroll
        for (int i = 0; i < 4; ++i) {
          int row = 16 * mt + 4 * lq + i;
          float pc = cacc[mt][i] + (float)pCH[row * 68 + oc];
          float cand = fast_tanh(pc);
          float u = (float)upk[mt * 2 + (i >> 1)][i & 1];
          float hr = (float)actA[row * 136 + 64 + oc];
          float hn = (m4[i] > 0.f) ? (1.f - u) * hr + u * cand : h[mt][i];
          h[mt][i] = hn;
          hquad[i] = (f16)hn;
        }
        *(f16x4*)(combT + (64 + oc) * 72 + 16 * mt + 4 * lq) = hquad;
        if (t == lenm1) {
#pragma unroll
          for (int i = 0; i < 4; ++i)
            out[((size_t)b * N_ + 16 * mt + 4 * lq + i) * D_ + oc] = h[mt][i];
        }
      }
    }
    __syncthreads();
  }
}

// ---------------------------------------------------------------------------
extern "C" void kernel_launch(void* const* d_in, const int* in_sizes, int n_in,
                              void* d_out, int out_size, void* d_ws, size_t ws_size,
                              hipStream_t stream) {
  const float* obs  = (const float*)d_in[0];
  const float* mask = (const float*)d_in[1];
  const int*   lens = (const int*)d_in[2];
  const float* ai   = (const float*)d_in[3];
  const float* vpr  = (const float*)d_in[4];
  const float* rarw = (const float*)d_in[5];
  const float* Wf1 = (const float*)d_in[6],  *bf1 = (const float*)d_in[7];
  const float* Wf2 = (const float*)d_in[8],  *bf2 = (const float*)d_in[9];
  const float* Wg1 = (const float*)d_in[10], *bg1 = (const float*)d_in[11];
  const float* Wg2 = (const float*)d_in[12], *bg2 = (const float*)d_in[13];
  const float* Wu = (const float*)d_in[14], *bu = (const float*)d_in[15];
  const float* Wr = (const float*)d_in[16], *br = (const float*)d_in[17];
  const float* Wc = (const float*)d_in[18], *bc = (const float*)d_in[19];

  char* p = (char*)d_ws;
  auto carve = [&](size_t bytes) {
    char* r = p;
    p += (bytes + 255) & ~(size_t)255;
    return r;
  };
  float* qv   = (float*)carve(N_ * Q_ * 4);
  float* neb  = (float*)carve(N_ * E_ * 4);
  f16x2* adjP = (f16x2*)carve(N_ * N_ * 4);
  float* brn  = (float*)carve(N_ * D_ * 4);
  float* bun  = (float*)carve(N_ * D_ * 4);
  float* bcn  = (float*)carve(N_ * D_ * 4);
  float* WrsR = (float*)carve(N_ * D_ * 4);
  float* WrsU = (float*)carve(N_ * D_ * 4);
  float* WrsC = (float*)carve(N_ * D_ * 4);
  float* vt   = (float*)carve(B_ * N_ * 4);
  f16* Wpk    = (f16*)carve((size_t)3 * 5 * 4 * 4 * 64 * 8 * 2);  // 245760 B

  k_mlps<<<N_, 256, 0, stream>>>(vpr, Wf1, bf1, Wf2, bf2, Wg1, bg1, Wg2, bg2, qv, neb);
  k_meta<<<N_, 64, 0, stream>>>(neb, qv, br, bu, bc, Wr, Wu, Wc, rarw,
                                adjP, brn, bun, bcn, WrsR, WrsU, WrsC);
  k_pack<<<240, 64, 0, stream>>>(Wr, Wu, Wc, Wpk);
  k_vt<<<B_, 64, 0, stream>>>(mask, vt);
  k_seq<<<B_, 512, 0, stream>>>(obs, mask, lens, ai, adjP,
                                brn, bun, bcn, WrsR, WrsU, WrsC,
                                qv, vt, Wpk, (float*)d_out);
}

// Round 4
// 2145.661 us; speedup vs baseline: 1.1893x; 1.1893x over previous
//
#include <hip/hip_runtime.h>
#include <cstddef>
#include <cstdint>

// Problem constants
#define B_ 64
#define T_ 128
#define N_ 64
#define D_ 64
#define Q_ 5
#define E_ 8
#define P_ 768
#define H_ 128

typedef _Float16 f16;
typedef _Float16 f16x2 __attribute__((ext_vector_type(2)));
typedef _Float16 f16x4 __attribute__((ext_vector_type(4)));
typedef _Float16 f16x8 __attribute__((ext_vector_type(8)));
typedef float f32x4 __attribute__((ext_vector_type(4)));

__device__ __forceinline__ float fast_sig(float x) {
  return 1.f / (1.f + __expf(-x));
}
__device__ __forceinline__ float fast_tanh(float x) {
  return 1.f - 2.f / (1.f + __expf(2.f * x));
}
__device__ __forceinline__ f16x8 splat8(f16 c) {
  return f16x8{c, c, c, c, c, c, c, c};
}

// ---------------------------------------------------------------------------
// K1: per-node MLPs -> qv (N,Q) and row-normalized ne (N,E). One block per n.
// ---------------------------------------------------------------------------
__global__ void k_mlps(const float* __restrict__ vpr,
                       const float* __restrict__ Wf1, const float* __restrict__ bf1,
                       const float* __restrict__ Wf2, const float* __restrict__ bf2,
                       const float* __restrict__ Wg1, const float* __restrict__ bg1,
                       const float* __restrict__ Wg2, const float* __restrict__ bg2,
                       float* __restrict__ qv, float* __restrict__ neb) {
  int n = blockIdx.x;
  int tid = threadIdx.x;  // 256
  __shared__ float v[P_];
  __shared__ float hf[H_];
  __shared__ float hg[H_];
  __shared__ float tmp[E_];

  for (int i = tid; i < P_; i += 256) v[i] = vpr[n * P_ + i];
  __syncthreads();

  if (tid < H_) {
    int j = tid;
    float a = bf1[j];
#pragma unroll 8
    for (int i = 0; i < P_; ++i) a += v[i] * Wf1[i * H_ + j];
    hf[j] = fmaxf(a, 0.f);
  } else {
    int j = tid - H_;
    float a = bg1[j];
#pragma unroll 8
    for (int i = 0; i < P_; ++i) a += v[i] * Wg1[i * H_ + j];
    hg[j] = fmaxf(a, 0.f);
  }
  __syncthreads();
  if (tid < Q_) {
    float a = bf2[tid];
    for (int j = 0; j < H_; ++j) a += hf[j] * Wf2[j * Q_ + tid];
    qv[n * Q_ + tid] = a;
  } else if (tid >= 8 && tid < 8 + E_) {
    int e = tid - 8;
    float a = bg2[e];
    for (int j = 0; j < H_; ++j) a += hg[j] * Wg2[j * E_ + e];
    tmp[e] = a;
  }
  __syncthreads();
  if (tid == 0) {
    float s = 0.f;
    for (int e = 0; e < E_; ++e) s += tmp[e] * tmp[e];
    float r = 1.f / sqrtf(s);
    for (int e = 0; e < E_; ++e) neb[n * E_ + e] = tmp[e] * r;
  }
}

// ---------------------------------------------------------------------------
// K2: adj row softmax -> adjP = f16x2{adj, adj*rarw}; per-node gate biases and
// rs-column weights (rank-1 fold of feature f=64). One block (64 thr) per n.
// ---------------------------------------------------------------------------
__global__ void k_meta(const float* __restrict__ neb, const float* __restrict__ qv,
                       const float* __restrict__ br, const float* __restrict__ bu,
                       const float* __restrict__ bc,
                       const float* __restrict__ Wr, const float* __restrict__ Wu,
                       const float* __restrict__ Wc, const float* __restrict__ rarw,
                       f16x2* __restrict__ adjP, float* __restrict__ brn,
                       float* __restrict__ bun, float* __restrict__ bcn,
                       float* __restrict__ WrsR, float* __restrict__ WrsU,
                       float* __restrict__ WrsC) {
  int n = blockIdx.x;
  int j = threadIdx.x;  // 64 = one wave
  float s = 0.f;
#pragma unroll
  for (int e = 0; e < E_; ++e) s += neb[n * E_ + e] * neb[j * E_ + e];
  float m = s;
  for (int off = 32; off; off >>= 1) m = fmaxf(m, __shfl_xor(m, off));
  float ex = __expf(s - m);
  float sum = ex;
  for (int off = 32; off; off >>= 1) sum += __shfl_xor(sum, off);
  float av = ex / sum;
  adjP[n * N_ + j] = f16x2{(f16)av, (f16)(av * rarw[n * N_ + j])};

  float pr = 0.f, pu = 0.f, pc = 0.f;
  float wr = 0.f, wu = 0.f, wc = 0.f;
#pragma unroll
  for (int q = 0; q < Q_; ++q) {
    float qq = qv[n * Q_ + q];
    pr += qq * br[q * D_ + j];
    pu += qq * bu[q * D_ + j];
    pc += qq * bc[q * D_ + j];
    wr += qq * Wr[((size_t)q * 129 + 64) * D_ + j];
    wu += qq * Wu[((size_t)q * 129 + 64) * D_ + j];
    wc += qq * Wc[((size_t)q * 129 + 64) * D_ + j];
  }
  brn[n * D_ + j] = pr;
  bun[n * D_ + j] = pu;
  bcn[n * D_ + j] = pc;
  WrsR[n * D_ + j] = wr;
  WrsU[n * D_ + j] = wu;
  WrsC[n * D_ + j] = wc;
}

// ---------------------------------------------------------------------------
// K3: pack shared gate weights into MFMA B-fragment order, fp16 (HW-verified
// in round 2 — do not change).
// frag id = ((g*5+q)*4+kt)*4+nt ; within frag lane l holds 8 f16:
//   B[k = 32*kt + 8*(l>>4) + e][col = 16*nt + (l&15)],  f = k + (k>=64)
// ---------------------------------------------------------------------------
__global__ void k_pack(const float* __restrict__ Wr, const float* __restrict__ Wu,
                       const float* __restrict__ Wc, f16* __restrict__ Wpk) {
  int bid = blockIdx.x;           // 240 = 3*5*4*4
  int nt = bid & 3;
  int kt = (bid >> 2) & 3;
  int q = (bid >> 4) % 5;
  int g = bid / 80;
  const float* W = (g == 0) ? Wr : ((g == 1) ? Wu : Wc);
  int l = threadIdx.x;            // 64
  int co = 16 * nt + (l & 15);
  f16* dst = Wpk + (size_t)bid * 512 + l * 8;
#pragma unroll
  for (int e = 0; e < 8; ++e) {
    int k = 32 * kt + 8 * (l >> 4) + e;
    int f = k + (k >= 64);
    dst[e] = (f16)W[((size_t)q * 129 + f) * D_ + co];
  }
}

// ---------------------------------------------------------------------------
// K4: var_total[b][n]
// ---------------------------------------------------------------------------
__global__ void k_vt(const float* __restrict__ mask, float* __restrict__ vt) {
  int b = blockIdx.x;
  int n = threadIdx.x;  // 64
  float s = 0.f;
  for (int t = 0; t < T_; ++t) s += mask[(b * T_ + t) * N_ + n];
  vt[b * N_ + n] = s;
}

// ---------------------------------------------------------------------------
// SEQ: one 256-thread block (4 waves, 1 wave/SIMD, forced 512-VGPR budget)
// per batch. Wave w owns output cols 16w..16w+15 for ALL 3 gates: 60 weight
// fragments (240 VGPRs) persist in registers across the whole T-loop.
// Each thread owns the C-layout cells (n=16mt+4lq+i, o=oc): u/r/h never
// leave registers; h_r round-trips LDS only because the c-gate GEMM mixes
// all columns. 5 barriers/step. LDS 62.2 KB static.
// ---------------------------------------------------------------------------
__global__ __launch_bounds__(256, 1) __attribute__((amdgpu_waves_per_eu(1, 1)))
void k_seq(const float* __restrict__ obs, const float* __restrict__ mask,
           const int* __restrict__ lengths, const float* __restrict__ ai,
           const f16x2* __restrict__ adjP,
           const float* __restrict__ brn, const float* __restrict__ bun,
           const float* __restrict__ bcn, const float* __restrict__ WrsR,
           const float* __restrict__ WrsU, const float* __restrict__ WrsC,
           const float* __restrict__ qv, const float* __restrict__ vt,
           const f16* __restrict__ Wpk, float* __restrict__ out) {
  // combT [feature k][node j] stride 72 (144B, 16B-aligned): rows 0..63 = x(d),
  // 64..127 = h(d)
  __shared__ __align__(16) f16 combT[128 * 72];   // 18432 B
  __shared__ __align__(16) f16 xA[64 * 72];       //  9216 B  x row-major [n][d]
  // actA [n][k] stride 168 (84 dw == 20 mod 32 -> spread): msg, written P2
  __shared__ __align__(16) f16 actA[64 * 168];    // 21504 B
  // AP [i][j] stride 88 (44 dw == 12 mod 32): A-matrix (P1..P2), then ALIASED
  // as h_r [n][o] (P4..P5)
  __shared__ __align__(16) f16 AP[64 * 88];       // 11264 B
  __shared__ __align__(16) f16 qvS[64 * 8];       //  1024 B
  __shared__ __align__(16) float rsS[N_];
  __shared__ __align__(16) float mS[N_];
  __shared__ __align__(16) float mrS[N_];

  const int tid = threadIdx.x;
  const int b = blockIdx.x;
  const int lane = tid & 63;
  const int wv = tid >> 6;        // 4 waves
  const int lm = lane & 15;
  const int lq = lane >> 4;
  const int oc = 16 * wv + lm;    // this wave's output column

  const int pn = tid >> 2;        // P0/P1/mr row (node / A-row)
  const int pj = 16 * (tid & 3);  // 16-wide j / d block

  // ---- persistent weight fragments: [gate][kt][q], 240 VGPRs ----
  f16x8 wW[3][4][5];
#pragma unroll
  for (int g = 0; g < 3; ++g)
#pragma unroll
    for (int kt = 0; kt < 4; ++kt)
#pragma unroll
      for (int q = 0; q < 5; ++q)
        wW[g][kt][q] = *(const f16x8*)(Wpk +
            ((size_t)(((g * 5 + q) * 4 + kt) * 4 + wv) * 64 + lane) * 8);

  // ---- persistent biases / rs-fold weights (C-layout cells) ----
  f16x2 bR[8], bU[8], bC[8], wRs[8], wUs[8], wCs[8];
#pragma unroll
  for (int mt = 0; mt < 4; ++mt)
#pragma unroll
    for (int ii = 0; ii < 2; ++ii) {
      int n0 = 16 * mt + 4 * lq + 2 * ii;
      bR[2 * mt + ii]  = f16x2{(f16)brn[n0 * D_ + oc],  (f16)brn[(n0 + 1) * D_ + oc]};
      bU[2 * mt + ii]  = f16x2{(f16)bun[n0 * D_ + oc],  (f16)bun[(n0 + 1) * D_ + oc]};
      bC[2 * mt + ii]  = f16x2{(f16)bcn[n0 * D_ + oc],  (f16)bcn[(n0 + 1) * D_ + oc]};
      wRs[2 * mt + ii] = f16x2{(f16)WrsR[n0 * D_ + oc], (f16)WrsR[(n0 + 1) * D_ + oc]};
      wUs[2 * mt + ii] = f16x2{(f16)WrsU[n0 * D_ + oc], (f16)WrsU[(n0 + 1) * D_ + oc]};
      wCs[2 * mt + ii] = f16x2{(f16)WrsC[n0 * D_ + oc], (f16)WrsC[(n0 + 1) * D_ + oc]};
    }

  // ---- persistent adjacency for this thread's A cells ----
  f16x2 adjR[16];
#pragma unroll
  for (int k = 0; k < 16; ++k) adjR[k] = adjP[pn * N_ + pj + k];

  // ---- qv staging -> qh fragments ----
#pragma unroll
  for (int u2 = 0; u2 < 2; ++u2) {
    int idx = 2 * tid + u2;
    int n = idx >> 3, q = idx & 7;
    qvS[idx] = (q < Q_) ? (f16)qv[n * Q_ + q] : (f16)0.f;
  }
  // zero combT h-rows (h(0)=0)
  for (int i = tid; i < 64 * 72; i += 256) combT[64 * 72 + i] = (f16)0.f;

  // persistent fp32 hidden state (C-layout)
  f32x4 h[4];
#pragma unroll
  for (int mt = 0; mt < 4; ++mt) h[mt] = f32x4{0.f, 0.f, 0.f, 0.f};

  // prefetch t=0 inputs
  const float* xb = obs + (size_t)b * T_ * (N_ * D_) + pn * D_ + pj;
  float4 xq0 = *(const float4*)(xb);
  float4 xq1 = *(const float4*)(xb + 4);
  float4 xq2 = *(const float4*)(xb + 8);
  float4 xq3 = *(const float4*)(xb + 12);
  float mCur = 0.f, aCur = 0.f, vtR = 0.f;
  if (tid < N_) {
    vtR = vt[b * N_ + tid];
    mCur = mask[(size_t)b * T_ * N_ + tid];
    aCur = ai[(size_t)b * T_ * N_ + tid];
  }
  const int lenm1 = lengths[b] - 1;
  __syncthreads();

  f16x8 qh[4];
#pragma unroll
  for (int mt = 0; mt < 4; ++mt) qh[mt] = *(const f16x8*)(qvS + (lm + 16 * mt) * 8);

  for (int t = 0; t < T_; ++t) {
    // ---- P0: rs/mask + x staging ----
    if (tid < N_) {
      mS[tid] = mCur;
      rsS[tid] = 0.5f * fast_tanh(aCur / (vtR + 1.f));
    }
    {
      f16x8 v0 = {(f16)xq0.x, (f16)xq0.y, (f16)xq0.z, (f16)xq0.w,
                  (f16)xq1.x, (f16)xq1.y, (f16)xq1.z, (f16)xq1.w};
      f16x8 v1 = {(f16)xq2.x, (f16)xq2.y, (f16)xq2.z, (f16)xq2.w,
                  (f16)xq3.x, (f16)xq3.y, (f16)xq3.z, (f16)xq3.w};
      *(f16x8*)(xA + pn * 72 + pj) = v0;
      *(f16x8*)(xA + pn * 72 + pj + 8) = v1;
    }
    __syncthreads();  // B1: xA, rsS, mS visible

    // ---- P1: build A -> AP ; transpose x -> combT rows 0..63 ----
    {
      float ri = rsS[pn], mi = mS[pn];
      f16x8 av0, av1;
#pragma unroll
      for (int k = 0; k < 16; ++k) {
        float a = ((float)adjR[k][0] -
                   (float)adjR[k][1] * fabsf(ri - rsS[pj + k])) * mi * mS[pj + k];
        if (pn == pj + k) a = 1.f;
        if (k < 8) av0[k] = (f16)a;
        else av1[k - 8] = (f16)a;
      }
      *(f16x8*)(AP + pn * 88 + pj) = av0;
      *(f16x8*)(AP + pn * 88 + pj + 8) = av1;

      // transpose: wave w handles node block n0=16w, lane = feature d.
      // reads are row-contiguous (conflict-free); writes are 2x b128/lane.
      int n0 = 16 * wv;
      f16x8 t0, t1;
#pragma unroll
      for (int k = 0; k < 8; ++k) t0[k] = xA[(n0 + k) * 72 + lane];
#pragma unroll
      for (int k = 0; k < 8; ++k) t1[k] = xA[(n0 + 8 + k) * 72 + lane];
      *(f16x8*)(combT + lane * 72 + n0) = t0;
      *(f16x8*)(combT + lane * 72 + n0 + 8) = t1;
    }
    __syncthreads();  // B2: AP, combT visible

    // ---- P2: msg = A @ [x;h] (8 MFMA-tiles/wave) ; mr = A @ rs ----
    {
#pragma unroll
      for (int s = 0; s < 2; ++s) {
        int ft = 2 * wv + s;
#pragma unroll
        for (int mt = 0; mt < 4; ++mt) {
          f32x4 acc = {0.f, 0.f, 0.f, 0.f};
#pragma unroll
          for (int kt = 0; kt < 2; ++kt) {
            f16x8 aF = *(const f16x8*)(AP + (lm + 16 * mt) * 88 + 8 * lq + 32 * kt);
            f16x8 bF = *(const f16x8*)(combT + (lm + 16 * ft) * 72 + 8 * lq + 32 * kt);
            acc = __builtin_amdgcn_mfma_f32_16x16x32_f16(aF, bF, acc, 0, 0, 0);
          }
          int row = 16 * mt + 4 * lq;
          int col = 16 * ft + lm;
          actA[(row + 0) * 168 + col] = (f16)acc[0];
          actA[(row + 1) * 168 + col] = (f16)acc[1];
          actA[(row + 2) * 168 + col] = (f16)acc[2];
          actA[(row + 3) * 168 + col] = (f16)acc[3];
        }
      }
      f16x8 a0 = *(const f16x8*)(AP + pn * 88 + pj);
      f16x8 a1 = *(const f16x8*)(AP + pn * 88 + pj + 8);
      float s = 0.f;
#pragma unroll
      for (int k = 0; k < 8; ++k)
        s += (float)a0[k] * rsS[pj + k] + (float)a1[k] * rsS[pj + 8 + k];
      s += __shfl_xor(s, 1);
      s += __shfl_xor(s, 2);
      if ((tid & 3) == 0) mrS[pn] = s;
    }
    __syncthreads();  // B3: actA(msg), mrS visible; AP free for h_r

    // ---- P3: r,u GEMMs (shared scaled A-fragments) ----
    f32x4 racc[4], uacc[4];
#pragma unroll
    for (int mt = 0; mt < 4; ++mt) {
      racc[mt] = f32x4{0.f, 0.f, 0.f, 0.f};
      uacc[mt] = f32x4{0.f, 0.f, 0.f, 0.f};
    }
#pragma unroll
    for (int kt = 0; kt < 4; ++kt) {
      f16x8 aF[4];
#pragma unroll
      for (int mt = 0; mt < 4; ++mt)
        aF[mt] = *(const f16x8*)(actA + (lm + 16 * mt) * 168 + 8 * lq + 32 * kt);
#pragma unroll
      for (int q = 0; q < 5; ++q) {
#pragma unroll
        for (int mt = 0; mt < 4; ++mt) {
          f16x8 as = aF[mt] * splat8(qh[mt][q]);
          racc[mt] = __builtin_amdgcn_mfma_f32_16x16x32_f16(as, wW[0][kt][q], racc[mt], 0, 0, 0);
          uacc[mt] = __builtin_amdgcn_mfma_f32_16x16x32_f16(as, wW[1][kt][q], uacc[mt], 0, 0, 0);
        }
      }
    }

    // ---- P4: elementwise r,u -> h_r ; write h_r into AP (no barrier needed
    // before: P3 reads actA, P4 writes AP) ----
    f16x2 upk[8], hrpk[8];
    {
#pragma unroll
      for (int mt = 0; mt < 4; ++mt) {
        float4 mr4 = *(const float4*)&mrS[16 * mt + 4 * lq];
        float4 m4 = *(const float4*)&mS[16 * mt + 4 * lq];
#pragma unroll
        for (int i = 0; i < 4; ++i) {
          int row = 16 * mt + 4 * lq + i;
          int ii = 2 * mt + (i >> 1);
          float pr = racc[mt][i] + (float)bR[ii][i & 1] + mr4[i] * (float)wRs[ii][i & 1];
          float pu = uacc[mt][i] + (float)bU[ii][i & 1] + mr4[i] * (float)wUs[ii][i & 1];
          float r = fast_sig(pr);
          float u = fast_sig(pu);
          float hr = (m4[i] > 0.f) ? r * h[mt][i] : h[mt][i];
          upk[ii][i & 1] = (f16)u;
          hrpk[ii][i & 1] = (f16)hr;
          AP[row * 88 + oc] = (f16)hr;
        }
      }
      // prefetch next step inputs (covered by P5 latency)
      if (t + 1 < T_) {
        const float* xn = xb + (size_t)(t + 1) * (N_ * D_);
        xq0 = *(const float4*)(xn);
        xq1 = *(const float4*)(xn + 4);
        xq2 = *(const float4*)(xn + 8);
        xq3 = *(const float4*)(xn + 12);
        if (tid < N_) {
          mCur = mask[((size_t)b * T_ + t + 1) * N_ + tid];
          aCur = ai[((size_t)b * T_ + t + 1) * N_ + tid];
        }
      }
    }
    __syncthreads();  // B4: h_r (in AP) visible

    // ---- P5: c GEMM (x-half from xA, h-half from AP-as-h_r) ----
    f32x4 cacc[4];
#pragma unroll
    for (int mt = 0; mt < 4; ++mt) cacc[mt] = f32x4{0.f, 0.f, 0.f, 0.f};
#pragma unroll
    for (int kt = 0; kt < 4; ++kt) {
      f16x8 aF[4];
#pragma unroll
      for (int mt = 0; mt < 4; ++mt) {
        if (kt < 2)
          aF[mt] = *(const f16x8*)(xA + (lm + 16 * mt) * 72 + 8 * lq + 32 * kt);
        else
          aF[mt] = *(const f16x8*)(AP + (lm + 16 * mt) * 88 + 8 * lq + 32 * (kt - 2));
      }
#pragma unroll
      for (int q = 0; q < 5; ++q) {
#pragma unroll
        for (int mt = 0; mt < 4; ++mt) {
          f16x8 as = aF[mt] * splat8(qh[mt][q]);
          cacc[mt] = __builtin_amdgcn_mfma_f32_16x16x32_f16(as, wW[2][kt][q], cacc[mt], 0, 0, 0);
        }
      }
    }

    // ---- P6: candidate, h update, combT h-rows, output ----
    {
#pragma unroll
      for (int mt = 0; mt < 4; ++mt) {
        float4 rs4 = *(const float4*)&rsS[16 * mt + 4 * lq];
        float4 m4 = *(const float4*)&mS[16 * mt + 4 * lq];
        f16x4 hq;
#pragma unroll
        for (int i = 0; i < 4; ++i) {
          int ii = 2 * mt + (i >> 1);
          float pc = cacc[mt][i] + (float)bC[ii][i & 1] + rs4[i] * (float)wCs[ii][i & 1];
          float cand = fast_tanh(pc);
          float u = (float)upk[ii][i & 1];
          float hr = (float)hrpk[ii][i & 1];
          float hn = (m4[i] > 0.f) ? (1.f - u) * hr + u * cand : h[mt][i];
          h[mt][i] = hn;
          hq[i] = (f16)hn;
        }
        *(f16x4*)(combT + (64 + oc) * 72 + 16 * mt + 4 * lq) = hq;
        if (t == lenm1) {
#pragma unroll
          for (int i = 0; i < 4; ++i)
            out[((size_t)b * N_ + 16 * mt + 4 * lq + i) * D_ + oc] = h[mt][i];
        }
      }
    }
    __syncthreads();  // B5: protect xA/rsS/mS/combT before next P0
  }
}

// ---------------------------------------------------------------------------
extern "C" void kernel_launch(void* const* d_in, const int* in_sizes, int n_in,
                              void* d_out, int out_size, void* d_ws, size_t ws_size,
                              hipStream_t stream) {
  const float* obs  = (const float*)d_in[0];
  const float* mask = (const float*)d_in[1];
  const int*   lens = (const int*)d_in[2];
  const float* ai   = (const float*)d_in[3];
  const float* vpr  = (const float*)d_in[4];
  const float* rarw = (const float*)d_in[5];
  const float* Wf1 = (const float*)d_in[6],  *bf1 = (const float*)d_in[7];
  const float* Wf2 = (const float*)d_in[8],  *bf2 = (const float*)d_in[9];
  const float* Wg1 = (const float*)d_in[10], *bg1 = (const float*)d_in[11];
  const float* Wg2 = (const float*)d_in[12], *bg2 = (const float*)d_in[13];
  const float* Wu = (const float*)d_in[14], *bu = (const float*)d_in[15];
  const float* Wr = (const float*)d_in[16], *br = (const float*)d_in[17];
  const float* Wc = (const float*)d_in[18], *bc = (const float*)d_in[19];

  char* p = (char*)d_ws;
  auto carve = [&](size_t bytes) {
    char* r = p;
    p += (bytes + 255) & ~(size_t)255;
    return r;
  };
  float* qv   = (float*)carve(N_ * Q_ * 4);
  float* neb  = (float*)carve(N_ * E_ * 4);
  f16x2* adjP = (f16x2*)carve(N_ * N_ * 4);
  float* brn  = (float*)carve(N_ * D_ * 4);
  float* bun  = (float*)carve(N_ * D_ * 4);
  float* bcn  = (float*)carve(N_ * D_ * 4);
  float* WrsR = (float*)carve(N_ * D_ * 4);
  float* WrsU = (float*)carve(N_ * D_ * 4);
  float* WrsC = (float*)carve(N_ * D_ * 4);
  float* vt   = (float*)carve(B_ * N_ * 4);
  f16* Wpk    = (f16*)carve((size_t)3 * 5 * 4 * 4 * 64 * 8 * 2);  // 245760 B

  k_mlps<<<N_, 256, 0, stream>>>(vpr, Wf1, bf1, Wf2, bf2, Wg1, bg1, Wg2, bg2, qv, neb);
  k_meta<<<N_, 64, 0, stream>>>(neb, qv, br, bu, bc, Wr, Wu, Wc, rarw,
                                adjP, brn, bun, bcn, WrsR, WrsU, WrsC);
  k_pack<<<240, 64, 0, stream>>>(Wr, Wu, Wc, Wpk);
  k_vt<<<B_, 64, 0, stream>>>(mask, vt);
  k_seq<<<B_, 256, 0, stream>>>(obs, mask, lens, ai, adjP,
                                brn, bun, bcn, WrsR, WrsU, WrsC,
                                qv, vt, Wpk, (float*)d_out);
}